// Round 7
// baseline (195.927 us; speedup 1.0000x reference)
//
#include <hip/hip_runtime.h>
#include <hip/hip_bf16.h>
#include <math.h>

#define NN 8192
#define DD 128
#define BIGF 3.402823466e+38f

typedef __attribute__((ext_vector_type(8))) short short8;
typedef __attribute__((ext_vector_type(4))) float f32x4;

static __device__ __forceinline__ void gll16(const void* g, void* l) {
    __builtin_amdgcn_global_load_lds(
        (const __attribute__((address_space(1))) void*)g,
        (__attribute__((address_space(3))) void*)l, 16, 0, 0);
}

static __device__ __forceinline__ unsigned short bfc(float f) {
    return __bfloat16_as_ushort(__float2bfloat16(f));
}

// ---------------- prep: fp32 -> bf16 + exact fp32 row norms + ws init ----------------
// 8 rows per block (thread t: row = blk*8 + t/32, float4 chunk = t%32). grid=(1024,2).
__global__ __launch_bounds__(256) void prep_kernel(const float* __restrict__ A,
                                                   const float* __restrict__ B,
                                                   __hip_bfloat16* __restrict__ Abf,
                                                   __hip_bfloat16* __restrict__ Bbf,
                                                   float* __restrict__ na,
                                                   float* __restrict__ nb,
                                                   unsigned int* __restrict__ minbuf,
                                                   float* __restrict__ partial) {
    // fold workspace init into this first kernel (dist_fused runs later on stream)
    if (blockIdx.y == 0 && blockIdx.x < 64) {
        minbuf[blockIdx.x * 256 + threadIdx.x] = 0xFFFFFFFFu;  // 16384 u32 = row+col mins
        if (blockIdx.x == 0 && threadIdx.x < 64) partial[threadIdx.x] = 0.f;
    }
    const float* x = blockIdx.y ? B : A;
    __hip_bfloat16* xb = blockIdx.y ? Bbf : Abf;
    float* norm = blockIdx.y ? nb : na;
    const int sub = threadIdx.x >> 5;   // row within block
    const int ch  = threadIdx.x & 31;   // float4 chunk
    const int row = blockIdx.x * 8 + sub;
    const float4 v = *(const float4*)(x + (size_t)row * DD + ch * 4);
    float s = v.x * v.x + v.y * v.y + v.z * v.z + v.w * v.w;
    uint2 pk;
    pk.x = ((unsigned)bfc(v.y) << 16) | bfc(v.x);
    pk.y = ((unsigned)bfc(v.w) << 16) | bfc(v.z);
    *(uint2*)(xb + (size_t)row * DD + ch * 4) = pk;
#pragma unroll
    for (int off = 16; off >= 1; off >>= 1) s += __shfl_xor(s, off, 64);  // 32-lane group
    if (ch == 0) norm[row] = s;
}

// ---------------- single fused MFMA distance pass ----------------
// loss algebra: hinge max(0, 1 - pos + d) is never clipped (d >= pos), so
// loss = 1 - 1/8192 + T/(N*M) - (P_r + P_c)/16384, with T = sum(d),
// P_r/P_c = sums of row/col mins. One pass: T via atomicAdd, mins via u32 atomicMin.
// 128x128 tile, 4 waves (2x2), each 64x64 = 4x4 frags of 16x16x32 bf16 MFMA.
// K in two 64-wide phases, 32 KB LDS. Staging via global_load_lds width=16:
// linear LDS dest, XOR-pre-swizzled GLOBAL source (LDS[r][c16] = G[r][c16^(r&7)]),
// so the swizzled read (conflict-free, 0 LDS conflicts measured) is unchanged.
__global__ __launch_bounds__(256, 4) void dist_fused(
    const __hip_bfloat16* __restrict__ Ab, const __hip_bfloat16* __restrict__ Bb,
    const float* __restrict__ na, const float* __restrict__ nb,
    unsigned int* __restrict__ rowmin, unsigned int* __restrict__ colmin,
    float* __restrict__ partial) {
    __shared__ char lds[32768];
    char* ldsA = lds;
    char* ldsB = lds + 16384;
    const int tid = threadIdx.x;
    const int l = tid & 63, wid = tid >> 6;
    const int rowBase = blockIdx.y * 128;
    const int colBase = blockIdx.x * 128;
    const char* aG = (const char*)Ab + (size_t)rowBase * 256;  // 256 B per row
    const char* bG = (const char*)Bb + (size_t)colBase * 256;

    // per-lane source offset for staging: row-sub (l>>3), chunk (l&7)^(l>>3)
    const int laneoff = ((l >> 3) << 8) + ((((l & 7) ^ (l >> 3))) << 4);
    const int wrow = wid * 32;          // this wave stages rows wrow..wrow+31

    const int wr = wid >> 1, wc = wid & 1;  // wave 64x64 sub-tile
    const int g = l >> 4, c = l & 15;

    f32x4 acc[4][4];
#pragma unroll
    for (int mi = 0; mi < 4; ++mi)
#pragma unroll
        for (int ni = 0; ni < 4; ++ni) acc[mi][ni] = (f32x4)0.f;

#pragma unroll
    for (int p = 0; p < 2; ++p) {
        if (p) __syncthreads();   // all waves done reading LDS before overwrite
        {
            const char* aP = aG + (size_t)wrow * 256 + p * 128 + laneoff;
            const char* bP = bG + (size_t)wrow * 256 + p * 128 + laneoff;
            char* lA = ldsA + wrow * 128;   // wave-uniform LDS bases
            char* lB = ldsB + wrow * 128;
#pragma unroll
            for (int i = 0; i < 4; ++i) {
                gll16(aP + i * 2048, lA + i * 1024);
                gll16(bP + i * 2048, lB + i * 1024);
            }
        }
        asm volatile("s_waitcnt vmcnt(0)" ::: "memory");
        __syncthreads();
#pragma unroll
        for (int kk = 0; kk < 2; ++kk) {
            short8 af[4], bf[4];
            const int kbyte = kk * 64 + g * 16;
#pragma unroll
            for (int mi = 0; mi < 4; ++mi) {
                int r = wr * 64 + mi * 16 + c;
                af[mi] = *(const short8*)(ldsA + r * 128 + (kbyte ^ ((r & 7) << 4)));
                int r2 = wc * 64 + mi * 16 + c;
                bf[mi] = *(const short8*)(ldsB + r2 * 128 + (kbyte ^ ((r2 & 7) << 4)));
            }
#pragma unroll
            for (int mi = 0; mi < 4; ++mi)
#pragma unroll
                for (int ni = 0; ni < 4; ++ni)
                    acc[mi][ni] = __builtin_amdgcn_mfma_f32_16x16x32_bf16(
                        af[mi], bf[ni], acc[mi][ni], 0, 0, 0);
        }
    }

    // out_row = row0 + mi*16 + g*4 + reg ; out_col = col0 + ni*16 + c
    const int row0 = rowBase + wr * 64;
    const int col0 = colBase + wc * 64;

    float nbc[4];
#pragma unroll
    for (int ni = 0; ni < 4; ++ni) nbc[ni] = nb[col0 + ni * 16 + c];

    float colm[4] = {BIGF, BIGF, BIGF, BIGF};
    f32x4 tot4 = (f32x4)0.f;
#pragma unroll
    for (int mi = 0; mi < 4; ++mi) {
        const f32x4 na4 = *(const f32x4*)(na + row0 + mi * 16 + g * 4);
        float dv[4][4];
#pragma unroll
        for (int ni = 0; ni < 4; ++ni) {
            f32x4 a = acc[mi][ni];
#pragma unroll
            for (int reg = 0; reg < 4; ++reg) {
                float d2 = fmaf(-2.0f, a[reg], na4[reg] + nbc[ni]);
                dv[ni][reg] = __builtin_amdgcn_sqrtf(fmaxf(d2, 0.f));
            }
        }
        // row mins: pair tree over ni, then 16-lane shuffle reduce
#pragma unroll
        for (int reg = 0; reg < 4; ++reg) {
            float m = fminf(fminf(dv[0][reg], dv[1][reg]),
                            fminf(dv[2][reg], dv[3][reg]));
            m = fminf(m, __shfl_xor(m, 1, 64));
            m = fminf(m, __shfl_xor(m, 2, 64));
            m = fminf(m, __shfl_xor(m, 4, 64));
            m = fminf(m, __shfl_xor(m, 8, 64));
            dv[0][reg] = m;  // reuse slot for atomic below
        }
        if (c == 0) {
#pragma unroll
            for (int reg = 0; reg < 4; ++reg)
                atomicMin(&rowmin[row0 + mi * 16 + g * 4 + reg],
                          __float_as_uint(dv[0][reg]));
        }
        // col mins + grand total (recompute-free: dv still holds d except dv[0],
        // whose min we already folded; use fresh reads of dv[1..3] + saved pre-min)
        // -> recompute col contribution from original values kept in regs:
        //    note dv[0][reg] was overwritten, so fold cols BEFORE? simpler: redo
        //    using acc again is costly; instead fold cols first next iteration.
        // To stay correct we compute cols/tot from a second copy below.
#pragma unroll
        for (int ni = 0; ni < 4; ++ni) {
            // recompute d for ni==0 lanes' overwritten entries is wrong; so
            // instead compute cols/tot from acc directly (cheap fma+sqrt reuse
            // avoided): recompute d2->d for ni row 0 only when needed.
            f32x4 a = acc[mi][ni];
            float d0, d1, d2v, d3;
            if (ni == 0) {
                d0 = __builtin_amdgcn_sqrtf(fmaxf(fmaf(-2.0f, a[0], na4[0] + nbc[0]), 0.f));
                d1 = __builtin_amdgcn_sqrtf(fmaxf(fmaf(-2.0f, a[1], na4[1] + nbc[0]), 0.f));
                d2v = __builtin_amdgcn_sqrtf(fmaxf(fmaf(-2.0f, a[2], na4[2] + nbc[0]), 0.f));
                d3 = __builtin_amdgcn_sqrtf(fmaxf(fmaf(-2.0f, a[3], na4[3] + nbc[0]), 0.f));
            } else {
                d0 = dv[ni][0]; d1 = dv[ni][1]; d2v = dv[ni][2]; d3 = dv[ni][3];
            }
            colm[ni] = fminf(colm[ni], fminf(fminf(d0, d1), fminf(d2v, d3)));
            tot4[0] += d0; tot4[1] += d1; tot4[2] += d2v; tot4[3] += d3;
        }
    }
    // col mins: reduce across the 4 g-groups
#pragma unroll
    for (int ni = 0; ni < 4; ++ni) {
        float m = colm[ni];
        m = fminf(m, __shfl_xor(m, 16, 64));
        m = fminf(m, __shfl_xor(m, 32, 64));
        if (g == 0) atomicMin(&colmin[col0 + ni * 16 + c], __float_as_uint(m));
    }
    // grand total: wave reduce then one atomicAdd per wave (no barriers)
    float tot = (tot4[0] + tot4[1]) + (tot4[2] + tot4[3]);
#pragma unroll
    for (int off = 32; off >= 1; off >>= 1) tot += __shfl_xor(tot, off, 64);
    if (l == 0) atomicAdd(&partial[blockIdx.y], tot);
}

// ---------------- finalize: combine mins + grand total into the scalar ----------------
__global__ __launch_bounds__(256) void finalize_kernel(const unsigned int* __restrict__ minbits,
                                                       const float* __restrict__ partial,
                                                       float* __restrict__ out) {
    const float* mins = (const float*)minbits;  // 16384 d-mins (rows then cols)
    float msum = 0.f;
    for (int i = threadIdx.x; i < 16384; i += 256) msum += mins[i];
    float cacc = msum * (-1.0f / 16384.0f);
    if (threadIdx.x < 64) cacc += partial[threadIdx.x] * (1.0f / 67108864.0f);
#pragma unroll
    for (int off = 32; off >= 1; off >>= 1) cacc += __shfl_xor(cacc, off, 64);
    __shared__ float red[4];
    int lane = threadIdx.x & 63, wave = threadIdx.x >> 6;
    if (lane == 0) red[wave] = cacc;
    __syncthreads();
    if (threadIdx.x == 0) {
        float t = red[0] + red[1] + red[2] + red[3];
        out[0] = t + 1.0f - 1.0f / 8192.0f;
    }
}

extern "C" void kernel_launch(void* const* d_in, const int* in_sizes, int n_in,
                              void* d_out, int out_size, void* d_ws, size_t ws_size,
                              hipStream_t stream) {
    const float* A = (const float*)d_in[0];
    const float* B = (const float*)d_in[1];
    char* ws = (char*)d_ws;

    const size_t MB = 1024 * 1024;
    __hip_bfloat16* Abf = (__hip_bfloat16*)(ws);                 // 2 MB
    __hip_bfloat16* Bbf = (__hip_bfloat16*)(ws + 2 * MB);        // 2 MB
    float* na            = (float*)(ws + 4 * MB);                // 32 KB
    float* nb            = (float*)(ws + 4 * MB + 32768);        // 32 KB
    unsigned int* rowmin = (unsigned int*)(ws + 4 * MB + 65536); // 32 KB
    unsigned int* colmin = (unsigned int*)(ws + 4 * MB + 98304); // 32 KB (contig after rowmin)
    float* partial       = (float*)(ws + 4 * MB + 131072);       // 256 B

    dim3 pgrid(NN / 8, 2);
    prep_kernel<<<pgrid, 256, 0, stream>>>(A, B, Abf, Bbf, na, nb, rowmin, partial);

    dim3 grid(NN / 128, NN / 128);
    dist_fused<<<grid, 256, 0, stream>>>(Abf, Bbf, na, nb, rowmin, colmin, partial);

    finalize_kernel<<<1, 256, 0, stream>>>(rowmin, partial, (float*)d_out);
}

// Round 8
// 188.420 us; speedup vs baseline: 1.0398x; 1.0398x over previous
//
#include <hip/hip_runtime.h>
#include <hip/hip_bf16.h>
#include <math.h>

#define NN 8192
#define DD 128
#define BIGF 3.402823466e+38f

typedef __attribute__((ext_vector_type(8))) short short8;
typedef __attribute__((ext_vector_type(4))) float f32x4;

static __device__ __forceinline__ unsigned short bfc(float f) {
    return __bfloat16_as_ushort(__float2bfloat16(f));
}

// ---------------- prep: fp32 -> bf16 + exact fp32 row norms + ws init ----------------
// 8 rows per block (thread t: row = blk*8 + t/32, float4 chunk = t%32). grid=(1024,2).
__global__ __launch_bounds__(256) void prep_kernel(const float* __restrict__ A,
                                                   const float* __restrict__ B,
                                                   __hip_bfloat16* __restrict__ Abf,
                                                   __hip_bfloat16* __restrict__ Bbf,
                                                   float* __restrict__ na,
                                                   float* __restrict__ nb,
                                                   unsigned int* __restrict__ minbuf,
                                                   float* __restrict__ partial) {
    // fold workspace init into this first kernel (dist_fused runs later on stream)
    if (blockIdx.y == 0 && blockIdx.x < 64) {
        minbuf[blockIdx.x * 256 + threadIdx.x] = 0xFFFFFFFFu;  // 16384 u32 = row+col mins
        if (blockIdx.x == 0 && threadIdx.x < 64) partial[threadIdx.x] = 0.f;
    }
    const float* x = blockIdx.y ? B : A;
    __hip_bfloat16* xb = blockIdx.y ? Bbf : Abf;
    float* norm = blockIdx.y ? nb : na;
    const int sub = threadIdx.x >> 5;   // row within block
    const int ch  = threadIdx.x & 31;   // float4 chunk
    const int row = blockIdx.x * 8 + sub;
    const float4 v = *(const float4*)(x + (size_t)row * DD + ch * 4);
    float s = v.x * v.x + v.y * v.y + v.z * v.z + v.w * v.w;
    uint2 pk;
    pk.x = ((unsigned)bfc(v.y) << 16) | bfc(v.x);
    pk.y = ((unsigned)bfc(v.w) << 16) | bfc(v.z);
    *(uint2*)(xb + (size_t)row * DD + ch * 4) = pk;
#pragma unroll
    for (int off = 16; off >= 1; off >>= 1) s += __shfl_xor(s, off, 64);  // 32-lane group
    if (ch == 0) norm[row] = s;
}

// ---------------- single fused MFMA distance pass, LDS-FREE ----------------
// loss algebra: hinge max(0, 1 - pos + d) is never clipped (d >= pos), so
// loss = 1 - 1/8192 + T/(N*M) - (P_r + P_c)/16384, with T = sum(d),
// P_r/P_c = sums of row/col mins. One pass: T via atomicAdd, mins via u32 atomicMin.
//
// No LDS, no barriers: for mfma_f32_16x16x32_bf16, lane (c=l&15, g=l>>4) needs
// A[row0+mi*16+c][kk*32+g*8 .. +7] = 16 contiguous bytes of the row-major row
// (same for B, which is stored [col][k]) -> fragments load directly from global
// as one dwordx4 per lane, 64B-segment coalesced. Inputs (2 MB each, bf16) are
// L2-resident, so tile reuse is handled by L2/L1 instead of LDS. Every wave is
// fully independent -> latency hidden by occupancy, zero sync stalls.
// 128x128 per block (4 waves, 2x2 of 64x64), grid 64x64.
__global__ __launch_bounds__(256, 2) void dist_fused(
    const __hip_bfloat16* __restrict__ Ab, const __hip_bfloat16* __restrict__ Bb,
    const float* __restrict__ na, const float* __restrict__ nb,
    unsigned int* __restrict__ rowmin, unsigned int* __restrict__ colmin,
    float* __restrict__ partial) {
    const int tid = threadIdx.x;
    const int l = tid & 63, wid = tid >> 6;
    const int wr = wid >> 1, wc = wid & 1;   // wave 64x64 sub-tile
    const int g = l >> 4, c = l & 15;
    const int row0 = blockIdx.y * 128 + wr * 64;
    const int col0 = blockIdx.x * 128 + wc * 64;

    // per-lane fragment base: row (row0+c), k-chunk g*16 bytes (256 B per row)
    const char* aB = (const char*)Ab + (size_t)(row0 + c) * 256 + g * 16;
    const char* bB = (const char*)Bb + (size_t)(col0 + c) * 256 + g * 16;

    f32x4 acc[4][4];
#pragma unroll
    for (int mi = 0; mi < 4; ++mi)
#pragma unroll
        for (int ni = 0; ni < 4; ++ni) acc[mi][ni] = (f32x4)0.f;

#pragma unroll
    for (int kk = 0; kk < 4; ++kk) {   // K = 128 = 4 x 32
        short8 af[4], bf[4];
#pragma unroll
        for (int mi = 0; mi < 4; ++mi) {
            af[mi] = *(const short8*)(aB + mi * 4096 + kk * 64);
            bf[mi] = *(const short8*)(bB + mi * 4096 + kk * 64);
        }
#pragma unroll
        for (int mi = 0; mi < 4; ++mi)
#pragma unroll
            for (int ni = 0; ni < 4; ++ni)
                acc[mi][ni] = __builtin_amdgcn_mfma_f32_16x16x32_bf16(
                    af[mi], bf[ni], acc[mi][ni], 0, 0, 0);
    }

    // out_row = row0 + mi*16 + g*4 + reg ; out_col = col0 + ni*16 + c
    float nbc[4];
#pragma unroll
    for (int ni = 0; ni < 4; ++ni) nbc[ni] = nb[col0 + ni * 16 + c];

    float colm[4] = {BIGF, BIGF, BIGF, BIGF};
    f32x4 tot4 = (f32x4)0.f;
#pragma unroll
    for (int mi = 0; mi < 4; ++mi) {
        const f32x4 na4 = *(const f32x4*)(na + row0 + mi * 16 + g * 4);
        float rowm[4] = {BIGF, BIGF, BIGF, BIGF};
#pragma unroll
        for (int ni = 0; ni < 4; ++ni) {
            f32x4 a = acc[mi][ni];
#pragma unroll
            for (int reg = 0; reg < 4; ++reg) {
                float d2 = fmaf(-2.0f, a[reg], na4[reg] + nbc[ni]);
                float d = __builtin_amdgcn_sqrtf(fmaxf(d2, 0.f));
                tot4[reg] += d;
                rowm[reg] = fminf(rowm[reg], d);
                colm[ni] = fminf(colm[ni], d);
            }
        }
        // row mins: reduce across the 16 c-lanes
#pragma unroll
        for (int reg = 0; reg < 4; ++reg) {
            float m = rowm[reg];
            m = fminf(m, __shfl_xor(m, 1, 64));
            m = fminf(m, __shfl_xor(m, 2, 64));
            m = fminf(m, __shfl_xor(m, 4, 64));
            m = fminf(m, __shfl_xor(m, 8, 64));
            rowm[reg] = m;
        }
        if (c == 0) {
#pragma unroll
            for (int reg = 0; reg < 4; ++reg)
                atomicMin(&rowmin[row0 + mi * 16 + g * 4 + reg],
                          __float_as_uint(rowm[reg]));
        }
    }
    // col mins: reduce across the 4 g-groups
#pragma unroll
    for (int ni = 0; ni < 4; ++ni) {
        float m = colm[ni];
        m = fminf(m, __shfl_xor(m, 16, 64));
        m = fminf(m, __shfl_xor(m, 32, 64));
        if (g == 0) atomicMin(&colmin[col0 + ni * 16 + c], __float_as_uint(m));
    }
    // grand total: wave reduce, one atomicAdd per wave (no barriers anywhere)
    float tot = (tot4[0] + tot4[1]) + (tot4[2] + tot4[3]);
#pragma unroll
    for (int off = 32; off >= 1; off >>= 1) tot += __shfl_xor(tot, off, 64);
    if (l == 0) atomicAdd(&partial[blockIdx.y], tot);
}

// ---------------- finalize: combine mins + grand total into the scalar ----------------
__global__ __launch_bounds__(256) void finalize_kernel(const unsigned int* __restrict__ minbits,
                                                       const float* __restrict__ partial,
                                                       float* __restrict__ out) {
    const float* mins = (const float*)minbits;  // 16384 d-mins (rows then cols)
    float msum = 0.f;
    for (int i = threadIdx.x; i < 16384; i += 256) msum += mins[i];
    float cacc = msum * (-1.0f / 16384.0f);
    if (threadIdx.x < 64) cacc += partial[threadIdx.x] * (1.0f / 67108864.0f);
#pragma unroll
    for (int off = 32; off >= 1; off >>= 1) cacc += __shfl_xor(cacc, off, 64);
    __shared__ float red[4];
    int lane = threadIdx.x & 63, wave = threadIdx.x >> 6;
    if (lane == 0) red[wave] = cacc;
    __syncthreads();
    if (threadIdx.x == 0) {
        float t = red[0] + red[1] + red[2] + red[3];
        out[0] = t + 1.0f - 1.0f / 8192.0f;
    }
}

extern "C" void kernel_launch(void* const* d_in, const int* in_sizes, int n_in,
                              void* d_out, int out_size, void* d_ws, size_t ws_size,
                              hipStream_t stream) {
    const float* A = (const float*)d_in[0];
    const float* B = (const float*)d_in[1];
    char* ws = (char*)d_ws;

    const size_t MB = 1024 * 1024;
    __hip_bfloat16* Abf = (__hip_bfloat16*)(ws);                 // 2 MB
    __hip_bfloat16* Bbf = (__hip_bfloat16*)(ws + 2 * MB);        // 2 MB
    float* na            = (float*)(ws + 4 * MB);                // 32 KB
    float* nb            = (float*)(ws + 4 * MB + 32768);        // 32 KB
    unsigned int* rowmin = (unsigned int*)(ws + 4 * MB + 65536); // 32 KB
    unsigned int* colmin = (unsigned int*)(ws + 4 * MB + 98304); // 32 KB (contig after rowmin)
    float* partial       = (float*)(ws + 4 * MB + 131072);       // 256 B

    dim3 pgrid(NN / 8, 2);
    prep_kernel<<<pgrid, 256, 0, stream>>>(A, B, Abf, Bbf, na, nb, rowmin, partial);

    dim3 grid(NN / 128, NN / 128);
    dist_fused<<<grid, 256, 0, stream>>>(Abf, Bbf, na, nb, rowmin, colmin, partial);

    finalize_kernel<<<1, 256, 0, stream>>>(rowmin, partial, (float*)d_out);
}